// Round 1
// baseline (311.677 us; speedup 1.0000x reference)
//
#include <hip/hip_runtime.h>
#include <hip/hip_bf16.h>

// VQ-VAE vector quantizer, MI355X — round 7.
// Round-6 diagnosis: both pipes idle (Mfma 16%, VALU 27%); the 2-pass screen
// doubles both the MFMA floor (33us) and the cb_swz L2 stream (2.1 GB ~ 60us
// at L2 ceiling). Fix: single-pass screen. Per-lane keys (code-dependent part
// m = 2*z.c - ||c||^2, |m| <= ~0.11) cached as truncated-bf16 pairs in 64
// VGPRs (kpk[16][2][2], fully unrolled => static indexing). Candidate scan
// reads the register cache instead of re-running MFMA+B-loads. Queue margin
// widened 3e-3 -> 3.8e-3 to absorb <=4.3e-4 bf16-trunc storage error; the
// fp32 refine (bit-identical to round-2 scheme) still picks the exact winner.
//
// d_out (float32): [0..16777215] z_q_st, [16777216] vq_loss, [+1..] indices.
// d_ws: [0,512K) cb_swz; [512K,+4K) c2; [528384,+16K) partials f64.

constexpr int D     = 256;
constexpr int NC    = 1024;
constexpr int NROWS = 65536;
constexpr int RPB   = 32;        // rows per block
constexpr int NBLK  = NROWS / RPB;   // 2048
constexpr int ZS    = 264;       // z_lds stride (floats)
constexpr int QCAP  = 512;       // block-wide candidate queue capacity
#define MARGIN_Q 3.8e-3f         // 3e-3 screen margin + 8e-4 bf16-store slack

typedef float accv4  __attribute__((ext_vector_type(4)));
typedef short short8 __attribute__((ext_vector_type(8)));

__device__ __forceinline__ short f2bf(float x) {
    __hip_bfloat16 h = __float2bfloat16(x);   // RNE (prep kernel only)
    return *reinterpret_cast<short*>(&h);
}
// pack truncated bf16(x) into low16, bf16(y) into high16 (2 VALU ops)
__device__ __forceinline__ unsigned packtrunc(float x, float y) {
    return (__float_as_uint(x) >> 16) | (__float_as_uint(y) & 0xffff0000u);
}

// numpy pairwise sum of x[0..127]^2 — 8-chain scheme (round-2 verified).
__device__ __forceinline__ float np_pairwise_sq128(const float* __restrict__ x) {
    float r[8];
    #pragma unroll
    for (int j = 0; j < 8; ++j) r[j] = __fmul_rn(x[j], x[j]);
    #pragma unroll
    for (int i = 8; i < 128; i += 8)
        #pragma unroll
        for (int j = 0; j < 8; ++j)
            r[j] = __fadd_rn(r[j], __fmul_rn(x[i + j], x[i + j]));
    float s01 = __fadd_rn(r[0], r[1]);
    float s23 = __fadd_rn(r[2], r[3]);
    float s45 = __fadd_rn(r[4], r[5]);
    float s67 = __fadd_rn(r[6], r[7]);
    return __fadd_rn(__fadd_rn(s01, s23), __fadd_rn(s45, s67));
}

// --- prep: per-code norms (round-2 identical) -------------------------------
__global__ void c2_kernel(const float* __restrict__ cb, float* __restrict__ c2) {
    int t = blockIdx.x * blockDim.x + threadIdx.x;
    if (t < NC) {
        const float* x = cb + (size_t)t * D;
        c2[t] = __fadd_rn(np_pairwise_sq128(x), np_pairwise_sq128(x + 128));
    }
}

// --- prep: swizzle codebook into MFMA B-fragment byte image -----------------
// short8 element t = tile*512 + ks*64 + lane holds
//   cb[tile*16 + (lane&15)][ks*32 + (lane>>4)*8 + j],  j=0..7
__global__ void swz_kernel(const float* __restrict__ cb, short* __restrict__ swz) {
    int t = blockIdx.x * blockDim.x + threadIdx.x;   // 0..32767
    int lane = t & 63, ts = t >> 6;
    int ks = ts & 7, tile = ts >> 3;
    int code = tile * 16 + (lane & 15);
    int kb   = ks * 32 + (lane >> 4) * 8;
    const float* src = cb + (size_t)code * D + kb;
    union { short s[8]; short8 v; } u;
    #pragma unroll
    for (int j = 0; j < 8; ++j) u.s[j] = f2bf(src[j]);
    *((short8*)swz + t) = u.v;
}

// --- main: 1-pass screen w/ register key-cache + flat refine + epilogue -----
__global__ __launch_bounds__(256, 2) void vq_kernel(
    const float* __restrict__ z,
    const float* __restrict__ cb,
    const short* __restrict__ cb_swz,
    const float* __restrict__ c2g,
    float*       __restrict__ out_zq,
    float*       __restrict__ out_idx,
    double*      __restrict__ partials)
{
    __shared__ __align__(16) float z_lds[RPB][ZS];     // 33792 B
    __shared__ float a_row[RPB];
    __shared__ __align__(16) float scratchA[RPB][4];   // A_n tree; then best64
    __shared__ float c2_lds[NC];                        // 4096 B
    __shared__ int   rm_shared[RPB];                    // approx min; then winners
    __shared__ __align__(16) int queue[QCAP];           // 2048 B; then f64 scratch
    __shared__ int   qn;

    const int tid     = threadIdx.x;
    const int lane    = tid & 63;
    const int w       = tid >> 6;         // wave 0..3
    const int rowBase = blockIdx.x * RPB;

    // ---- phase 1: stage z (fp32), c2, init ----
    #pragma unroll
    for (int j = 0; j < 8; ++j) {
        int l = tid + 256 * j;
        int row = l >> 6, q = l & 63;
        float4 v = *(const float4*)(z + (size_t)(rowBase + row) * D + q * 4);
        *(float4*)&z_lds[row][q * 4] = v;
    }
    #pragma unroll
    for (int j = 0; j < 4; ++j) c2_lds[tid + 256 * j] = c2g[tid + 256 * j];
    if (tid < RPB) rm_shared[tid] = 0x7f800000;   // +inf
    if (tid == 0)  qn = 0;
    __syncthreads();

    // ---- phase 2: A_n (numpy pairwise, round-2-exact tree), 4 threads/row ----
    if (tid < RPB * 4) {
        int row = tid >> 2, q = tid & 3;
        int h = (q >> 1) * 128, p = (q & 1) * 4;
        const float* x = &z_lds[row][0];
        float r0 = __fmul_rn(x[h+p+0], x[h+p+0]);
        float r1 = __fmul_rn(x[h+p+1], x[h+p+1]);
        float r2 = __fmul_rn(x[h+p+2], x[h+p+2]);
        float r3 = __fmul_rn(x[h+p+3], x[h+p+3]);
        #pragma unroll
        for (int i = 8; i < 128; i += 8) {
            r0 = __fadd_rn(r0, __fmul_rn(x[h+i+p+0], x[h+i+p+0]));
            r1 = __fadd_rn(r1, __fmul_rn(x[h+i+p+1], x[h+i+p+1]));
            r2 = __fadd_rn(r2, __fmul_rn(x[h+i+p+2], x[h+i+p+2]));
            r3 = __fadd_rn(r3, __fmul_rn(x[h+i+p+3], x[h+i+p+3]));
        }
        scratchA[row][q] = __fadd_rn(__fadd_rn(r0, r1), __fadd_rn(r2, r3));
    }
    __syncthreads();
    if (tid < RPB) {
        float half0 = __fadd_rn(scratchA[tid][0], scratchA[tid][1]);
        float half1 = __fadd_rn(scratchA[tid][2], scratchA[tid][3]);
        a_row[tid]  = __fadd_rn(half0, half1);
    }
    __syncthreads();

    // ---- phase 3: A-fragments from GLOBAL z (truncated bf16, no LDS) ----
    // lane L, row-tile rt, k-slice ks: rows rt*16+(L&15), dims ks*32+(L>>4)*8..+7
    short8 afrag[2][8];
    #pragma unroll
    for (int rt = 0; rt < 2; ++rt)
        #pragma unroll
        for (int ks = 0; ks < 8; ++ks) {
            const float* src = z + (size_t)(rowBase + rt * 16 + (lane & 15)) * D
                                 + ks * 32 + (lane >> 4) * 8;
            float4 v0 = *(const float4*)(src);
            float4 v1 = *(const float4*)(src + 4);
            union { unsigned u[4]; short8 v; } pk;
            pk.u[0] = packtrunc(v0.x, v0.y);
            pk.u[1] = packtrunc(v0.z, v0.w);
            pk.u[2] = packtrunc(v1.x, v1.y);
            pk.u[3] = packtrunc(v1.z, v1.w);
            afrag[rt][ks] = pk.v;
        }
    float a_reg[2][4];
    #pragma unroll
    for (int rt = 0; rt < 2; ++rt)
        #pragma unroll
        for (int i = 0; i < 4; ++i)
            a_reg[rt][i] = a_row[rt * 16 + (lane >> 4) * 4 + i];

    // ---- phase 4: SINGLE-pass MFMA screen, keys cached as packed bf16 ----
    // key(row,code) = a - m  with  m = 2*(z.c)_bf16 - ||c||^2.
    // runmin tracked in fp32; m stored truncated-bf16 (err <= 4.3e-4 < margin).
    float runmin[2][4];
    #pragma unroll
    for (int rt = 0; rt < 2; ++rt)
        #pragma unroll
        for (int i = 0; i < 4; ++i) runmin[rt][i] = 3.4e38f;

    unsigned kpk[16][2][2];          // [tile-step][rt][pair] — 64 VGPRs
    const short8* bbase = (const short8*)cb_swz + lane;
    short8 bcur[8];
    #pragma unroll
    for (int ks = 0; ks < 8; ++ks) bcur[ks] = bbase[(size_t)w * 512 + ks * 64];

    #pragma unroll
    for (int t = 0; t < 16; ++t) {
        const int tile = w + 4 * t;
        short8 bnxt[8];
        if (t < 15) {
            #pragma unroll
            for (int ks = 0; ks < 8; ++ks)
                bnxt[ks] = bbase[(size_t)(tile + 4) * 512 + ks * 64];
        }
        accv4 acc[2];
        #pragma unroll
        for (int rt = 0; rt < 2; ++rt) acc[rt] = (accv4){0.f, 0.f, 0.f, 0.f};
        #pragma unroll
        for (int ks = 0; ks < 8; ++ks) {
            #pragma unroll
            for (int rt = 0; rt < 2; ++rt)
                acc[rt] = __builtin_amdgcn_mfma_f32_16x16x32_bf16(
                    afrag[rt][ks], bcur[ks], acc[rt], 0, 0, 0);
        }
        const float c2v = c2_lds[tile * 16 + (lane & 15)];
        #pragma unroll
        for (int rt = 0; rt < 2; ++rt) {
            float m0 = fmaf(2.0f, acc[rt][0], -c2v);
            float m1 = fmaf(2.0f, acc[rt][1], -c2v);
            float m2 = fmaf(2.0f, acc[rt][2], -c2v);
            float m3 = fmaf(2.0f, acc[rt][3], -c2v);
            kpk[t][rt][0] = packtrunc(m0, m1);
            kpk[t][rt][1] = packtrunc(m2, m3);
            runmin[rt][0] = fminf(runmin[rt][0], a_reg[rt][0] - m0);
            runmin[rt][1] = fminf(runmin[rt][1], a_reg[rt][1] - m1);
            runmin[rt][2] = fminf(runmin[rt][2], a_reg[rt][2] - m2);
            runmin[rt][3] = fminf(runmin[rt][3], a_reg[rt][3] - m3);
        }
        if (t < 15) {
            #pragma unroll
            for (int ks = 0; ks < 8; ++ks) bcur[ks] = bnxt[ks];
        }
    }

    // row-min reduce across the 16 cols of each quadrant, then across waves
    #pragma unroll
    for (int rt = 0; rt < 2; ++rt)
        #pragma unroll
        for (int i = 0; i < 4; ++i) {
            float m = runmin[rt][i];
            m = fminf(m, __shfl_xor(m, 1));
            m = fminf(m, __shfl_xor(m, 2));
            m = fminf(m, __shfl_xor(m, 4));
            m = fminf(m, __shfl_xor(m, 8));
            if ((lane & 15) == 0) {
                int row = rt * 16 + (lane >> 4) * 4 + i;
                atomicMin(&rm_shared[row], __float_as_int(m));
            }
        }
    __syncthreads();

    // ---- phase 4b: scan register key-cache, enqueue candidates ----
    // key <= min + MARGIN_Q  <=>  m >= a - (min + MARGIN_Q) = mthr
    float mthr[2][4];
    #pragma unroll
    for (int rt = 0; rt < 2; ++rt)
        #pragma unroll
        for (int i = 0; i < 4; ++i) {
            int row = rt * 16 + (lane >> 4) * 4 + i;
            mthr[rt][i] = a_reg[rt][i]
                        - (__int_as_float(rm_shared[row]) + MARGIN_Q);
        }
    #pragma unroll
    for (int t = 0; t < 16; ++t) {
        const int code = (w + 4 * t) * 16 + (lane & 15);
        #pragma unroll
        for (int rt = 0; rt < 2; ++rt)
            #pragma unroll
            for (int pr = 0; pr < 2; ++pr) {
                unsigned pk = kpk[t][rt][pr];
                float mlo = __uint_as_float(pk << 16);
                float mhi = __uint_as_float(pk & 0xffff0000u);
                if (mlo >= mthr[rt][2 * pr]) {
                    int row  = rt * 16 + (lane >> 4) * 4 + 2 * pr;
                    int slot = atomicAdd(&qn, 1);
                    if (slot < QCAP) queue[slot] = (row << 10) | code;
                }
                if (mhi >= mthr[rt][2 * pr + 1]) {
                    int row  = rt * 16 + (lane >> 4) * 4 + 2 * pr + 1;
                    int slot = atomicAdd(&qn, 1);
                    if (slot < QCAP) queue[slot] = (row << 10) | code;
                }
            }
    }

    // ---- phase 5: exact refinement (bit-identical to round-2 keys) ----
    unsigned long long* best64 = (unsigned long long*)&scratchA[0][0];
    if (tid < RPB) best64[tid] = ~0ull;
    __syncthreads();
    int total = qn;
    if (total <= QCAP) {
        for (int t = tid; t < total; t += 256) {
            int e = queue[t];
            int row = e >> 10, code = e & 1023;
            const float4* cp = (const float4*)(cb + (size_t)code * D);
            const float*  zr = &z_lds[row][0];
            float acc = 0.0f;
            #pragma unroll 8
            for (int d4 = 0; d4 < 64; ++d4) {
                float4 cv = cp[d4];
                acc = fmaf(zr[d4 * 4 + 0], cv.x, acc);
                acc = fmaf(zr[d4 * 4 + 1], cv.y, acc);
                acc = fmaf(zr[d4 * 4 + 2], cv.z, acc);
                acc = fmaf(zr[d4 * 4 + 3], cv.w, acc);
            }
            float key = __fsub_rn(__fadd_rn(a_row[row], c2_lds[code]), 2.0f * acc);
            unsigned long long pk =
                ((unsigned long long)__float_as_uint(key) << 32) | (unsigned)code;
            atomicMin(&best64[row], pk);
        }
    } else {
        for (int r = 0; r < RPB; ++r) {
            for (int c = tid; c < NC; c += 256) {
                const float4* cp = (const float4*)(cb + (size_t)c * D);
                const float*  zr = &z_lds[r][0];
                float acc = 0.0f;
                #pragma unroll 8
                for (int d4 = 0; d4 < 64; ++d4) {
                    float4 cv = cp[d4];
                    acc = fmaf(zr[d4 * 4 + 0], cv.x, acc);
                    acc = fmaf(zr[d4 * 4 + 1], cv.y, acc);
                    acc = fmaf(zr[d4 * 4 + 2], cv.z, acc);
                    acc = fmaf(zr[d4 * 4 + 3], cv.w, acc);
                }
                float key = __fsub_rn(__fadd_rn(a_row[r], c2_lds[c]), 2.0f * acc);
                unsigned long long pk =
                    ((unsigned long long)__float_as_uint(key) << 32) | (unsigned)c;
                atomicMin(&best64[r], pk);
            }
        }
    }
    __syncthreads();

    // ---- phase 6: winners ----
    int* winner = rm_shared;   // reuse
    if (tid < RPB) {
        unsigned long long b = best64[tid];
        int wdx = (b == ~0ull) ? 0 : (int)(b & 0xffffffffu);
        winner[tid] = wdx;
        out_idx[rowBase + tid] = (float)wdx;
    }
    __syncthreads();

    // ---- phase 7: vectorized epilogue (float4 path, wave-uniform row) ----
    double lacc = 0.0;
    #pragma unroll
    for (int j = 0; j < 8; ++j) {
        int idx = tid + 256 * j;      // 0..2047
        int row = idx >> 6;           // wave-uniform
        int q4  = idx & 63;
        int wd  = winner[row];
        float4 cv = *(const float4*)(cb + (size_t)wd * D + q4 * 4);
        float4 zv = *(const float4*)&z_lds[row][q4 * 4];
        float4 o;
        o.x = __fadd_rn(zv.x, __fsub_rn(cv.x, zv.x));
        o.y = __fadd_rn(zv.y, __fsub_rn(cv.y, zv.y));
        o.z = __fadd_rn(zv.z, __fsub_rn(cv.z, zv.z));
        o.w = __fadd_rn(zv.w, __fsub_rn(cv.w, zv.w));
        *(float4*)(out_zq + (size_t)(rowBase + row) * D + q4 * 4) = o;
        double d0 = (double)zv.x - (double)cv.x;
        double d1 = (double)zv.y - (double)cv.y;
        double d2 = (double)zv.z - (double)cv.z;
        double d3 = (double)zv.w - (double)cv.w;
        lacc += d0 * d0 + d1 * d1 + d2 * d2 + d3 * d3;
    }
    __syncthreads();
    double* dred = (double*)&queue[0];   // 512 ints = 256 doubles
    dred[tid] = lacc;
    __syncthreads();
    for (int s = 128; s > 0; s >>= 1) {
        if (tid < s) dred[tid] += dred[tid + s];
        __syncthreads();
    }
    if (tid == 0) partials[blockIdx.x] = dred[0];
}

// --- final loss reduction ---------------------------------------------------
__global__ void loss_kernel(const double* __restrict__ partials,
                            float* __restrict__ out_loss)
{
    __shared__ double sm[256];
    int tid = threadIdx.x;
    double s = 0.0;
    for (int i = tid; i < NBLK; i += 256) s += partials[i];
    sm[tid] = s;
    __syncthreads();
    for (int k = 128; k > 0; k >>= 1) {
        if (tid < k) sm[tid] += sm[tid + k];
        __syncthreads();
    }
    if (tid == 0)
        out_loss[0] = (float)(1.25 * sm[0] / (double)((size_t)NROWS * D));
}

extern "C" void kernel_launch(void* const* d_in, const int* in_sizes, int n_in,
                              void* d_out, int out_size, void* d_ws, size_t ws_size,
                              hipStream_t stream)
{
    const float* z  = (const float*)d_in[0];   // [65536, 256]
    const float* cb = (const float*)d_in[1];   // [1024, 256]

    float* out      = (float*)d_out;
    float* out_zq   = out;
    float* out_loss = out + (size_t)NROWS * D;
    float* out_idx  = out_loss + 1;

    char*   ws       = (char*)d_ws;
    short*  cb_swz   = (short*)ws;                       // 512 KB
    float*  c2       = (float*)(ws + 524288);            // 4 KB
    double* partials = (double*)(ws + 528384);           // 16 KB

    swz_kernel<<<128, 256, 0, stream>>>(cb, cb_swz);
    c2_kernel<<<4, 256, 0, stream>>>(cb, c2);
    vq_kernel<<<NBLK, 256, 0, stream>>>(z, cb, cb_swz, c2,
                                        out_zq, out_idx, partials);
    loss_kernel<<<1, 256, 0, stream>>>(partials, out_loss);
}

// Round 2
// 279.361 us; speedup vs baseline: 1.1157x; 1.1157x over previous
//
#include <hip/hip_runtime.h>
#include <hip/hip_bf16.h>

// VQ-VAE vector quantizer, MI355X — round 8.
// Round-7 post-mortem: 64-VGPR key cache spilled (VGPR pinned 128; FETCH +34MB,
// WRITE +59MB scratch). Round 8 keeps the single-pass screen but replaces the
// big cache with ONLINE enqueue: rm_shared only decreases, so any stale
// threshold is a conservative-correct filter. Bootstrap steps 0-1 cache keys
// in 8 VGPRs (kpk[2][2][2]); one barrier publishes the first threshold; steps
// 2-15 enqueue online with a threshold refresh (shfl-reduce + LDS atomicMin,
// barrier-free) every 4 steps. 1x MFMA + 1x cb_swz L2 stream vs round-6's 2x.
// Exact fp32 refine + overflow fallback unchanged -> bit-identical winners.
//
// d_out (float32): [0..16777215] z_q_st, [16777216] vq_loss, [+1..] indices.
// d_ws: [0,512K) cb_swz; [512K,+4K) c2; [528384,+16K) partials f64.

constexpr int D     = 256;
constexpr int NC    = 1024;
constexpr int NROWS = 65536;
constexpr int RPB   = 32;        // rows per block
constexpr int NBLK  = NROWS / RPB;   // 2048
constexpr int ZS    = 264;       // z_lds stride (floats)
constexpr int QCAP  = 1024;      // block-wide candidate queue capacity
#define MARGIN_Q 3.8e-3f         // 3e-3 screen margin + 8e-4 bf16-store slack

typedef float accv4  __attribute__((ext_vector_type(4)));
typedef short short8 __attribute__((ext_vector_type(8)));

__device__ __forceinline__ short f2bf(float x) {
    __hip_bfloat16 h = __float2bfloat16(x);   // RNE (prep kernel only)
    return *reinterpret_cast<short*>(&h);
}
// pack truncated bf16(x) into low16, bf16(y) into high16 (2 VALU ops)
__device__ __forceinline__ unsigned packtrunc(float x, float y) {
    return (__float_as_uint(x) >> 16) | (__float_as_uint(y) & 0xffff0000u);
}

// numpy pairwise sum of x[0..127]^2 — 8-chain scheme (round-2 verified).
__device__ __forceinline__ float np_pairwise_sq128(const float* __restrict__ x) {
    float r[8];
    #pragma unroll
    for (int j = 0; j < 8; ++j) r[j] = __fmul_rn(x[j], x[j]);
    #pragma unroll
    for (int i = 8; i < 128; i += 8)
        #pragma unroll
        for (int j = 0; j < 8; ++j)
            r[j] = __fadd_rn(r[j], __fmul_rn(x[i + j], x[i + j]));
    float s01 = __fadd_rn(r[0], r[1]);
    float s23 = __fadd_rn(r[2], r[3]);
    float s45 = __fadd_rn(r[4], r[5]);
    float s67 = __fadd_rn(r[6], r[7]);
    return __fadd_rn(__fadd_rn(s01, s23), __fadd_rn(s45, s67));
}

// --- prep: per-code norms (round-2 identical) -------------------------------
__global__ void c2_kernel(const float* __restrict__ cb, float* __restrict__ c2) {
    int t = blockIdx.x * blockDim.x + threadIdx.x;
    if (t < NC) {
        const float* x = cb + (size_t)t * D;
        c2[t] = __fadd_rn(np_pairwise_sq128(x), np_pairwise_sq128(x + 128));
    }
}

// --- prep: swizzle codebook into MFMA B-fragment byte image -----------------
// short8 element t = tile*512 + ks*64 + lane holds
//   cb[tile*16 + (lane&15)][ks*32 + (lane>>4)*8 + j],  j=0..7
__global__ void swz_kernel(const float* __restrict__ cb, short* __restrict__ swz) {
    int t = blockIdx.x * blockDim.x + threadIdx.x;   // 0..32767
    int lane = t & 63, ts = t >> 6;
    int ks = ts & 7, tile = ts >> 3;
    int code = tile * 16 + (lane & 15);
    int kb   = ks * 32 + (lane >> 4) * 8;
    const float* src = cb + (size_t)code * D + kb;
    union { short s[8]; short8 v; } u;
    #pragma unroll
    for (int j = 0; j < 8; ++j) u.s[j] = f2bf(src[j]);
    *((short8*)swz + t) = u.v;
}

// --- main: 1-pass screen (online enqueue) + flat refine + epilogue ----------
__global__ __launch_bounds__(256, 2) void vq_kernel(
    const float* __restrict__ z,
    const float* __restrict__ cb,
    const short* __restrict__ cb_swz,
    const float* __restrict__ c2g,
    float*       __restrict__ out_zq,
    float*       __restrict__ out_idx,
    double*      __restrict__ partials)
{
    __shared__ __align__(16) float z_lds[RPB][ZS];     // 33792 B
    __shared__ float a_row[RPB];
    __shared__ __align__(16) float scratchA[RPB][4];   // A_n tree; then best64
    __shared__ float c2_lds[NC];                        // 4096 B
    __shared__ int   rm_shared[RPB];                    // approx min; then winners
    __shared__ __align__(16) int queue[QCAP];           // 4096 B; then f64 scratch
    __shared__ int   qn;

    const int tid     = threadIdx.x;
    const int lane    = tid & 63;
    const int w       = tid >> 6;         // wave 0..3
    const int rowBase = blockIdx.x * RPB;

    // ---- phase 1: stage z (fp32), c2, init ----
    #pragma unroll
    for (int j = 0; j < 8; ++j) {
        int l = tid + 256 * j;
        int row = l >> 6, q = l & 63;
        float4 v = *(const float4*)(z + (size_t)(rowBase + row) * D + q * 4);
        *(float4*)&z_lds[row][q * 4] = v;
    }
    #pragma unroll
    for (int j = 0; j < 4; ++j) c2_lds[tid + 256 * j] = c2g[tid + 256 * j];
    if (tid < RPB) rm_shared[tid] = 0x7f800000;   // +inf
    if (tid == 0)  qn = 0;
    __syncthreads();

    // ---- phase 2: A_n (numpy pairwise, round-2-exact tree), 4 threads/row ----
    if (tid < RPB * 4) {
        int row = tid >> 2, q = tid & 3;
        int h = (q >> 1) * 128, p = (q & 1) * 4;
        const float* x = &z_lds[row][0];
        float r0 = __fmul_rn(x[h+p+0], x[h+p+0]);
        float r1 = __fmul_rn(x[h+p+1], x[h+p+1]);
        float r2 = __fmul_rn(x[h+p+2], x[h+p+2]);
        float r3 = __fmul_rn(x[h+p+3], x[h+p+3]);
        #pragma unroll
        for (int i = 8; i < 128; i += 8) {
            r0 = __fadd_rn(r0, __fmul_rn(x[h+i+p+0], x[h+i+p+0]));
            r1 = __fadd_rn(r1, __fmul_rn(x[h+i+p+1], x[h+i+p+1]));
            r2 = __fadd_rn(r2, __fmul_rn(x[h+i+p+2], x[h+i+p+2]));
            r3 = __fadd_rn(r3, __fmul_rn(x[h+i+p+3], x[h+i+p+3]));
        }
        scratchA[row][q] = __fadd_rn(__fadd_rn(r0, r1), __fadd_rn(r2, r3));
    }
    __syncthreads();
    if (tid < RPB) {
        float half0 = __fadd_rn(scratchA[tid][0], scratchA[tid][1]);
        float half1 = __fadd_rn(scratchA[tid][2], scratchA[tid][3]);
        a_row[tid]  = __fadd_rn(half0, half1);
    }
    __syncthreads();

    // ---- phase 3: A-fragments from GLOBAL z (truncated bf16, no LDS) ----
    // lane L, row-tile rt, k-slice ks: rows rt*16+(L&15), dims ks*32+(L>>4)*8..+7
    short8 afrag[2][8];
    #pragma unroll
    for (int rt = 0; rt < 2; ++rt)
        #pragma unroll
        for (int ks = 0; ks < 8; ++ks) {
            const float* src = z + (size_t)(rowBase + rt * 16 + (lane & 15)) * D
                                 + ks * 32 + (lane >> 4) * 8;
            float4 v0 = *(const float4*)(src);
            float4 v1 = *(const float4*)(src + 4);
            union { unsigned u[4]; short8 v; } pk;
            pk.u[0] = packtrunc(v0.x, v0.y);
            pk.u[1] = packtrunc(v0.z, v0.w);
            pk.u[2] = packtrunc(v1.x, v1.y);
            pk.u[3] = packtrunc(v1.z, v1.w);
            afrag[rt][ks] = pk.v;
        }
    float a_reg[2][4];
    #pragma unroll
    for (int rt = 0; rt < 2; ++rt)
        #pragma unroll
        for (int i = 0; i < 4; ++i)
            a_reg[rt][i] = a_row[rt * 16 + (lane >> 4) * 4 + i];

    // ---- phase 4: SINGLE-pass MFMA screen with online enqueue ----
    // key(row,code) = a - m,  m = 2*(z.c)_bf16 - ||c||^2.
    // rm_shared only decreases => stale thresholds are conservative-correct.
    float runmin[2][4];
    #pragma unroll
    for (int rt = 0; rt < 2; ++rt)
        #pragma unroll
        for (int i = 0; i < 4; ++i) runmin[rt][i] = 3.4e38f;

    const short8* bbase = (const short8*)cb_swz + lane;
    short8 bcur[8];
    #pragma unroll
    for (int ks = 0; ks < 8; ++ks) bcur[ks] = bbase[(size_t)w * 512 + ks * 64];

    // -- bootstrap: steps 0..1, keys cached in 8 VGPRs --
    unsigned kpk[2][2][2];
    #pragma unroll
    for (int t = 0; t < 2; ++t) {
        const int tile = w + 4 * t;
        short8 bnxt[8];
        #pragma unroll
        for (int ks = 0; ks < 8; ++ks)
            bnxt[ks] = bbase[(size_t)(tile + 4) * 512 + ks * 64];
        accv4 acc[2];
        #pragma unroll
        for (int rt = 0; rt < 2; ++rt) acc[rt] = (accv4){0.f, 0.f, 0.f, 0.f};
        #pragma unroll
        for (int ks = 0; ks < 8; ++ks) {
            #pragma unroll
            for (int rt = 0; rt < 2; ++rt)
                acc[rt] = __builtin_amdgcn_mfma_f32_16x16x32_bf16(
                    afrag[rt][ks], bcur[ks], acc[rt], 0, 0, 0);
        }
        const float c2v = c2_lds[tile * 16 + (lane & 15)];
        #pragma unroll
        for (int rt = 0; rt < 2; ++rt) {
            float m0 = fmaf(2.0f, acc[rt][0], -c2v);
            float m1 = fmaf(2.0f, acc[rt][1], -c2v);
            float m2 = fmaf(2.0f, acc[rt][2], -c2v);
            float m3 = fmaf(2.0f, acc[rt][3], -c2v);
            kpk[t][rt][0] = packtrunc(m0, m1);
            kpk[t][rt][1] = packtrunc(m2, m3);
            runmin[rt][0] = fminf(runmin[rt][0], a_reg[rt][0] - m0);
            runmin[rt][1] = fminf(runmin[rt][1], a_reg[rt][1] - m1);
            runmin[rt][2] = fminf(runmin[rt][2], a_reg[rt][2] - m2);
            runmin[rt][3] = fminf(runmin[rt][3], a_reg[rt][3] - m3);
        }
        #pragma unroll
        for (int ks = 0; ks < 8; ++ks) bcur[ks] = bnxt[ks];
    }

    // publish bootstrap mins (all waves), one barrier for a good first thr
    #pragma unroll
    for (int rt = 0; rt < 2; ++rt)
        #pragma unroll
        for (int i = 0; i < 4; ++i) {
            float m = runmin[rt][i];
            m = fminf(m, __shfl_xor(m, 1));
            m = fminf(m, __shfl_xor(m, 2));
            m = fminf(m, __shfl_xor(m, 4));
            m = fminf(m, __shfl_xor(m, 8));
            if ((lane & 15) == 0) {
                int row = rt * 16 + (lane >> 4) * 4 + i;
                atomicMin(&rm_shared[row], __float_as_int(m));
            }
        }
    __syncthreads();

    float mthr[2][4];      // enqueue iff m >= mthr  (<=> key <= min + margin)
    #pragma unroll
    for (int rt = 0; rt < 2; ++rt)
        #pragma unroll
        for (int i = 0; i < 4; ++i) {
            int row = rt * 16 + (lane >> 4) * 4 + i;
            mthr[rt][i] = a_reg[rt][i]
                        - (__int_as_float(rm_shared[row]) + MARGIN_Q);
        }

    // scan the 2-step bootstrap cache
    #pragma unroll
    for (int t = 0; t < 2; ++t) {
        const int code = (w + 4 * t) * 16 + (lane & 15);
        #pragma unroll
        for (int rt = 0; rt < 2; ++rt)
            #pragma unroll
            for (int pr = 0; pr < 2; ++pr) {
                unsigned pk = kpk[t][rt][pr];
                float mlo = __uint_as_float(pk << 16);
                float mhi = __uint_as_float(pk & 0xffff0000u);
                if (mlo >= mthr[rt][2 * pr]) {
                    int row  = rt * 16 + (lane >> 4) * 4 + 2 * pr;
                    int slot = atomicAdd(&qn, 1);
                    if (slot < QCAP) queue[slot] = (row << 10) | code;
                }
                if (mhi >= mthr[rt][2 * pr + 1]) {
                    int row  = rt * 16 + (lane >> 4) * 4 + 2 * pr + 1;
                    int slot = atomicAdd(&qn, 1);
                    if (slot < QCAP) queue[slot] = (row << 10) | code;
                }
            }
    }

    // -- online: steps 2..15, enqueue as we go, refresh thr every 4 steps --
    for (int t = 2; t < 16; ++t) {
        const int tile = w + 4 * t;
        short8 bnxt[8];
        if (t < 15) {
            #pragma unroll
            for (int ks = 0; ks < 8; ++ks)
                bnxt[ks] = bbase[(size_t)(tile + 4) * 512 + ks * 64];
        }
        accv4 acc[2];
        #pragma unroll
        for (int rt = 0; rt < 2; ++rt) acc[rt] = (accv4){0.f, 0.f, 0.f, 0.f};
        #pragma unroll
        for (int ks = 0; ks < 8; ++ks) {
            #pragma unroll
            for (int rt = 0; rt < 2; ++rt)
                acc[rt] = __builtin_amdgcn_mfma_f32_16x16x32_bf16(
                    afrag[rt][ks], bcur[ks], acc[rt], 0, 0, 0);
        }
        const float c2v  = c2_lds[tile * 16 + (lane & 15)];
        const int   code = tile * 16 + (lane & 15);
        #pragma unroll
        for (int rt = 0; rt < 2; ++rt) {
            #pragma unroll
            for (int i = 0; i < 4; ++i) {
                float m = fmaf(2.0f, acc[rt][i], -c2v);
                runmin[rt][i] = fminf(runmin[rt][i], a_reg[rt][i] - m);
                if (m >= mthr[rt][i]) {
                    int row  = rt * 16 + (lane >> 4) * 4 + i;
                    int slot = atomicAdd(&qn, 1);
                    if (slot < QCAP) queue[slot] = (row << 10) | code;
                }
            }
        }
        if (t == 5 || t == 9 || t == 13) {   // barrier-free threshold refresh
            #pragma unroll
            for (int rt = 0; rt < 2; ++rt)
                #pragma unroll
                for (int i = 0; i < 4; ++i) {
                    float m = runmin[rt][i];
                    m = fminf(m, __shfl_xor(m, 1));
                    m = fminf(m, __shfl_xor(m, 2));
                    m = fminf(m, __shfl_xor(m, 4));
                    m = fminf(m, __shfl_xor(m, 8));
                    if ((lane & 15) == 0) {
                        int row = rt * 16 + (lane >> 4) * 4 + i;
                        atomicMin(&rm_shared[row], __float_as_int(m));
                    }
                }
            #pragma unroll
            for (int rt = 0; rt < 2; ++rt)
                #pragma unroll
                for (int i = 0; i < 4; ++i) {
                    int row = rt * 16 + (lane >> 4) * 4 + i;
                    mthr[rt][i] = a_reg[rt][i]
                                - (__int_as_float(rm_shared[row]) + MARGIN_Q);
                }
        }
        if (t < 15) {
            #pragma unroll
            for (int ks = 0; ks < 8; ++ks) bcur[ks] = bnxt[ks];
        }
    }

    // ---- phase 5: exact refinement (bit-identical to round-2 keys) ----
    unsigned long long* best64 = (unsigned long long*)&scratchA[0][0];
    if (tid < RPB) best64[tid] = ~0ull;
    __syncthreads();
    int total = qn;
    if (total <= QCAP) {
        for (int t = tid; t < total; t += 256) {
            int e = queue[t];
            int row = e >> 10, code = e & 1023;
            const float4* cp = (const float4*)(cb + (size_t)code * D);
            const float*  zr = &z_lds[row][0];
            float acc = 0.0f;
            #pragma unroll 8
            for (int d4 = 0; d4 < 64; ++d4) {
                float4 cv = cp[d4];
                acc = fmaf(zr[d4 * 4 + 0], cv.x, acc);
                acc = fmaf(zr[d4 * 4 + 1], cv.y, acc);
                acc = fmaf(zr[d4 * 4 + 2], cv.z, acc);
                acc = fmaf(zr[d4 * 4 + 3], cv.w, acc);
            }
            float key = __fsub_rn(__fadd_rn(a_row[row], c2_lds[code]), 2.0f * acc);
            unsigned long long pk =
                ((unsigned long long)__float_as_uint(key) << 32) | (unsigned)code;
            atomicMin(&best64[row], pk);
        }
    } else {
        for (int r = 0; r < RPB; ++r) {
            for (int c = tid; c < NC; c += 256) {
                const float4* cp = (const float4*)(cb + (size_t)c * D);
                const float*  zr = &z_lds[r][0];
                float acc = 0.0f;
                #pragma unroll 8
                for (int d4 = 0; d4 < 64; ++d4) {
                    float4 cv = cp[d4];
                    acc = fmaf(zr[d4 * 4 + 0], cv.x, acc);
                    acc = fmaf(zr[d4 * 4 + 1], cv.y, acc);
                    acc = fmaf(zr[d4 * 4 + 2], cv.z, acc);
                    acc = fmaf(zr[d4 * 4 + 3], cv.w, acc);
                }
                float key = __fsub_rn(__fadd_rn(a_row[r], c2_lds[c]), 2.0f * acc);
                unsigned long long pk =
                    ((unsigned long long)__float_as_uint(key) << 32) | (unsigned)c;
                atomicMin(&best64[r], pk);
            }
        }
    }
    __syncthreads();

    // ---- phase 6: winners ----
    int* winner = rm_shared;   // reuse
    if (tid < RPB) {
        unsigned long long b = best64[tid];
        int wdx = (b == ~0ull) ? 0 : (int)(b & 0xffffffffu);
        winner[tid] = wdx;
        out_idx[rowBase + tid] = (float)wdx;
    }
    __syncthreads();

    // ---- phase 7: vectorized epilogue (float4 path, wave-uniform row) ----
    double lacc = 0.0;
    #pragma unroll
    for (int j = 0; j < 8; ++j) {
        int idx = tid + 256 * j;      // 0..2047
        int row = idx >> 6;           // wave-uniform
        int q4  = idx & 63;
        int wd  = winner[row];
        float4 cv = *(const float4*)(cb + (size_t)wd * D + q4 * 4);
        float4 zv = *(const float4*)&z_lds[row][q4 * 4];
        float4 o;
        o.x = __fadd_rn(zv.x, __fsub_rn(cv.x, zv.x));
        o.y = __fadd_rn(zv.y, __fsub_rn(cv.y, zv.y));
        o.z = __fadd_rn(zv.z, __fsub_rn(cv.z, zv.z));
        o.w = __fadd_rn(zv.w, __fsub_rn(cv.w, zv.w));
        *(float4*)(out_zq + (size_t)(rowBase + row) * D + q4 * 4) = o;
        double d0 = (double)zv.x - (double)cv.x;
        double d1 = (double)zv.y - (double)cv.y;
        double d2 = (double)zv.z - (double)cv.z;
        double d3 = (double)zv.w - (double)cv.w;
        lacc += d0 * d0 + d1 * d1 + d2 * d2 + d3 * d3;
    }
    __syncthreads();
    double* dred = (double*)&queue[0];   // 256 doubles = 2048 B, fits in queue
    dred[tid] = lacc;
    __syncthreads();
    for (int s = 128; s > 0; s >>= 1) {
        if (tid < s) dred[tid] += dred[tid + s];
        __syncthreads();
    }
    if (tid == 0) partials[blockIdx.x] = dred[0];
}

// --- final loss reduction ---------------------------------------------------
__global__ void loss_kernel(const double* __restrict__ partials,
                            float* __restrict__ out_loss)
{
    __shared__ double sm[256];
    int tid = threadIdx.x;
    double s = 0.0;
    for (int i = tid; i < NBLK; i += 256) s += partials[i];
    sm[tid] = s;
    __syncthreads();
    for (int k = 128; k > 0; k >>= 1) {
        if (tid < k) sm[tid] += sm[tid + k];
        __syncthreads();
    }
    if (tid == 0)
        out_loss[0] = (float)(1.25 * sm[0] / (double)((size_t)NROWS * D));
}

extern "C" void kernel_launch(void* const* d_in, const int* in_sizes, int n_in,
                              void* d_out, int out_size, void* d_ws, size_t ws_size,
                              hipStream_t stream)
{
    const float* z  = (const float*)d_in[0];   // [65536, 256]
    const float* cb = (const float*)d_in[1];   // [1024, 256]

    float* out      = (float*)d_out;
    float* out_zq   = out;
    float* out_loss = out + (size_t)NROWS * D;
    float* out_idx  = out_loss + 1;

    char*   ws       = (char*)d_ws;
    short*  cb_swz   = (short*)ws;                       // 512 KB
    float*  c2       = (float*)(ws + 524288);            // 4 KB
    double* partials = (double*)(ws + 528384);           // 16 KB

    swz_kernel<<<128, 256, 0, stream>>>(cb, cb_swz);
    c2_kernel<<<4, 256, 0, stream>>>(cb, c2);
    vq_kernel<<<NBLK, 256, 0, stream>>>(z, cb, cb_swz, c2,
                                        out_zq, out_idx, partials);
    loss_kernel<<<1, 256, 0, stream>>>(partials, out_loss);
}